// Round 16
// baseline (132.794 us; speedup 1.0000x reference)
//
#include <hip/hip_runtime.h>
#include <math.h>

#define NV 720
#define NU 736
#define NUP 768      // padded Q row stride (bins 736..767 never gathered)
#define NXY 512

// ---------------- Stage 1+2: cosine weight + Ram-Lak Toeplitz GEMM (+ trig, + out=0) ---
__global__ __launch_bounds__(192) void filter_kernel(const float* __restrict__ sino,
                                                     float* __restrict__ Q,
                                                     float4* __restrict__ trig,
                                                     float* __restrict__ out_zero) {
    __shared__ float s4[2][368][4];   // [parity][m][view]
    __shared__ float wco[736];        // wco[i] = -1/(pi*(2i-735)*DU)^2
    const int v0 = blockIdx.x * 4;
    const int t = threadIdx.x;

    for (int i = blockIdx.x * 192 + t; i < NXY * NXY; i += 180 * 192)
        out_zero[i] = 0.0f;

    if (t < 4) {
        int v = v0 + t;
        float beta = (float)((double)v * (2.0 * M_PI / 720.0));
        float cb = cosf(beta), sb = sinf(beta);
        const float K = (float)(1085.6 / 1.2858);   // DSD/DU
        trig[v] = make_float4(cb * K, sb * K, cb, sb);
    }
    for (int i = t; i < 736; i += 192) {
        double n = (double)(2 * i - 735);
        double a = M_PI * n * 1.2858;
        wco[i] = (float)(-1.0 / (a * a));
    }
    const float DSD2 = (float)(1085.6 * 1085.6);
    for (int vv = 0; vv < 4; ++vv) {
        for (int u = t; u < 736; u += 192) {
            float us = ((float)u - 367.5f) * 1.2858f;
            float cw = 1085.6f / sqrtf(DSD2 + us * us);
            s4[u & 1][u >> 1][vv] = sino[(v0 + vv) * NU + u] * cw;
        }
    }
    __syncthreads();

    if (t < 184) {
        const int pj = (t < 92) ? 1 : 0;
        const int J0 = (t < 92) ? t : t - 92;
        const int q = 1 - pj;
        float acc[4][4];
        #pragma unroll
        for (int r = 0; r < 4; ++r)
            #pragma unroll
            for (int vv = 0; vv < 4; ++vv) acc[r][vv] = 0.0f;

        const int ibase0 = J0 + 367 + pj;
        #pragma unroll 4
        for (int m = 0; m < 368; ++m) {
            const float4 sv = *(const float4*)&s4[q][m][0];
            const int ib = ibase0 - m;
            const float w0 = wco[ib];
            const float w1 = wco[ib + 92];
            const float w2 = wco[ib + 184];
            const float w3 = wco[ib + 276];
            acc[0][0] = fmaf(w0, sv.x, acc[0][0]);
            acc[0][1] = fmaf(w0, sv.y, acc[0][1]);
            acc[0][2] = fmaf(w0, sv.z, acc[0][2]);
            acc[0][3] = fmaf(w0, sv.w, acc[0][3]);
            acc[1][0] = fmaf(w1, sv.x, acc[1][0]);
            acc[1][1] = fmaf(w1, sv.y, acc[1][1]);
            acc[1][2] = fmaf(w1, sv.z, acc[1][2]);
            acc[1][3] = fmaf(w1, sv.w, acc[1][3]);
            acc[2][0] = fmaf(w2, sv.x, acc[2][0]);
            acc[2][1] = fmaf(w2, sv.y, acc[2][1]);
            acc[2][2] = fmaf(w2, sv.z, acc[2][2]);
            acc[2][3] = fmaf(w2, sv.w, acc[2][3]);
            acc[3][0] = fmaf(w3, sv.x, acc[3][0]);
            acc[3][1] = fmaf(w3, sv.y, acc[3][1]);
            acc[3][2] = fmaf(w3, sv.z, acc[3][2]);
            acc[3][3] = fmaf(w3, sv.w, acc[3][3]);
        }
        const float H0 = (float)(1.0 / (4.0 * 1.2858 * 1.2858));
        #pragma unroll
        for (int r = 0; r < 4; ++r) {
            const float4 c = *(const float4*)&s4[pj][J0 + 92 * r][0];
            acc[r][0] = fmaf(H0, c.x, acc[r][0]);
            acc[r][1] = fmaf(H0, c.y, acc[r][1]);
            acc[r][2] = fmaf(H0, c.z, acc[r][2]);
            acc[r][3] = fmaf(H0, c.w, acc[r][3]);
        }
        #pragma unroll
        for (int r = 0; r < 4; ++r) {
            const int j = 2 * (J0 + 92 * r) + pj;
            #pragma unroll
            for (int vv = 0; vv < 4; ++vv)
                Q[(v0 + vv) * NUP + j] = acc[r][vv] * 1.2858f;
        }
    }
}

// ---------------- Stage 3: backprojection — hybrid DS + VMEM gathers -------------------
// Calibrated model (R14/R15): ds_read2_b32 ~7.5cyc -> DS crossbar ~40us is the binding
// per-CU resource; VMEM/TA pipe (divergence resolution ~11cyc/wave-load, R6/R8) is IDLE.
// THIS ROUND: split the 16 gathers/iter 10 DS : 6 VMEM (optimal max(10*7.5+stage,6*11))
// -> gather critical path per wave-iter ~144 -> ~81 cyc. The 6 VMEM gathers read the
// SAME Q elements directly (L2-hot) with the SAME fma chains and summation order ->
// bit-identical. Loads are unconditional in-loop (R12 lesson: no branch-wrapped fetch).
// Exterior waves unchanged (R3-exact gates, R4 lesson). Dbuf staging kept (R15).
__global__ __launch_bounds__(256) void bp_kernel(const float* __restrict__ Q,
                                                 const float4* __restrict__ trig,
                                                 float* __restrict__ out) {
    __shared__ float win[2][4][NUP];          // 24 KB double buffer
    const int b = blockIdx.x;
    const int c = b & 15;                     // view chunk: base views {c, c+16, ...}
    const int blk = b >> 4;                   // 256 quadrant blocks of 16x16
    const int bx = blk >> 4;
    const int by = blk & 15;
    const int t = threadIdx.x;
    const int w = t >> 6;
    const int l = t & 63;
    const int iq = (bx << 4) + ((w >> 1) << 3) + (l >> 3);   // [0,256)
    const int jq = (by << 4) + ((w & 1) << 3) + (l & 7);     // [0,256)

    const float dx = 400.0f / 512.0f;         // 0.78125 exact
    const float X = ((float)iq - 255.5f) * dx;   // < 0
    const float Y = ((float)jq - 255.5f) * dx;   // < 0
    const float Kc = (float)(1085.6 / 1.2858);

    float acc0 = 0.0f, acc1 = 0.0f, acc2 = 0.0f, acc3 = 0.0f;
    const bool inr = fmaf(X, X, Y * Y) <= 236.5f * 236.5f;
    const bool myint = __all(inr);

    const int nk = (c < 4) ? 12 : 11;         // ceil((180-c)/16)
    const float* rowp = Q + (size_t)(c + 180 * w) * NUP;   // wave w stages row w
    const float* qb = Q + (size_t)c * NUP;    // current base-view row (for VMEM gathers)
    const float4* tvp = trig + c;

    // preload iter 0 into buffer 0
    #pragma unroll
    for (int ch = 0; ch < 3; ++ch)
        __builtin_amdgcn_global_load_lds(
            (const __attribute__((address_space(1))) void*)(rowp + ch * 256 + l * 4),
            (__attribute__((address_space(3))) void*)&win[0][w][ch * 256],
            16, 0, 0);

    for (int it = 0; it < nk; ++it) {
        __syncthreads();                      // win[it&1] staged; prior reads of it^1 done
        if (it + 1 < nk) {
            const float* rn = rowp + 16 * NUP;
            #pragma unroll
            for (int ch = 0; ch < 3; ++ch)
                __builtin_amdgcn_global_load_lds(
                    (const __attribute__((address_space(1))) void*)(rn + ch * 256 + l * 4),
                    (__attribute__((address_space(3))) void*)&win[(it + 1) & 1][w][ch * 256],
                    16, 0, 0);
        }
        const float* winf = &win[it & 1][0][0];

        if (myint) {
            // ---- interior: symmetric geometry (R10-proven); 10 DS + 6 VMEM gathers ---
            const float4 tv = tvp[0];                     // cb = tv.z, sb = tv.w
            float a = fmaf(tv.z, X, tv.w * Y);            // t0
            float bb = fmaf(tv.z, Y, -tv.w * X);          // s0
            float aK = a * Kc, bK = bb * Kc;
            float D0 = 595.0f - bb, D1 = 595.0f + a, D2 = 595.0f + bb, D3 = 595.0f - a;
            float r0 = __builtin_amdgcn_rcpf(D0);
            float r1 = __builtin_amdgcn_rcpf(D1);
            float r2 = __builtin_amdgcn_rcpf(D2);
            float r3 = __builtin_amdgcn_rcpf(D3);
            float fi0 = fmaf(aK,  r0, 367.5f);
            float fi1 = fmaf(bK,  r1, 367.5f);
            float fi2 = fmaf(-aK, r2, 367.5f);
            float fi3 = fmaf(-bK, r3, 367.5f);
            int im[4] = {(int)fi0, (int)fi1, (int)fi2, (int)fi3};  // in [1,733]
            float ff[4] = {__builtin_amdgcn_fractf(fi0), __builtin_amdgcn_fractf(fi1),
                           __builtin_amdgcn_fractf(fi2), __builtin_amdgcn_fractf(fi3)};
            float gg[4] = {r0 * r0, r1 * r1, r2 * r2, r3 * r3};
            float* accp[4] = {&acc0, &acc1, &acc2, &acc3};
            #pragma unroll
            for (int m = 0; m < 4; ++m) {
                #pragma unroll
                for (int k = 0; k < 4; ++k) {
                    float q0, q1;
                    if (m * 4 + k < 10) {                 // DS path (staged LDS)
                        const float* p = winf + (k * NUP + im[m]);
                        q0 = p[0];                        // ds_read2_b32
                        q1 = p[1];
                    } else {                              // VMEM path (divergent, L2-hot)
                        float2 qq = *(const float2*)(qb + (size_t)(k * 180) * NUP + im[m]);
                        q0 = qq.x;                        // global_load_dwordx2
                        q1 = qq.y;
                    }
                    float val = fmaf(ff[m], q1 - q0, q0);
                    *accp[(m - k) & 3] = fmaf(gg[m], val, *accp[(m - k) & 3]);
                }
            }
        } else {
            // ---- exterior: R3-exact chains/gates per pixel, staged ds_read2 fetch ----
            const float4 tvs[4] = {tvp[0], tvp[180], tvp[360], tvp[540]};
            const float pX[4] = {X, Y, -X, -Y};
            const float pY[4] = {Y, -X, -Y, X};
            float* accp[4] = {&acc0, &acc1, &acc2, &acc3};
            #pragma unroll
            for (int j = 0; j < 4; ++j) {
                float Xm = pX[j], Ym = pY[j];
                #pragma unroll
                for (int k = 0; k < 4; ++k) {
                    const float4 tv = tvs[k];
                    float t2 = fmaf(tv.x, Xm, tv.y * Ym);               // R3-exact
                    float D  = fmaf(tv.w, Xm, fmaf(tv.z, -Ym, 595.0f)); // R3-exact
                    float rD = __builtin_amdgcn_rcpf(D);
                    float fidx = fmaf(t2, rD, 367.5f);
                    int i0c = min(max((int)fidx, 0), NU - 2);           // v_med3_i32
                    float f = __builtin_amdgcn_fractf(fidx);
                    const float* p = winf + (k * NUP + i0c);
                    float q0 = p[0];                                    // ds_read2_b32
                    float q1 = p[1];
                    float val = fmaf(f, q1 - q0, q0);
                    float cen = fidx - 367.5f;                          // R3-exact gate
                    float g = (__builtin_fabsf(cen) <= 367.5f) ? rD * rD : 0.0f;
                    *accp[j] = fmaf(g, val, *accp[j]);
                }
            }
        }
        rowp += 16 * NUP;
        qb += 16 * NUP;
        tvp += 16;
    }
    const float SC = (float)(595.0 * 595.0 * 0.5 * (2.0 * M_PI / 720.0));
    const int ir = 511 - iq, jr = 511 - jq;
    unsafeAtomicAdd(&out[iq * NXY + jq], acc0 * SC);   // P0 = (iq, jq)
    unsafeAtomicAdd(&out[jq * NXY + ir], acc1 * SC);   // P1 = (jq, 511-iq)
    unsafeAtomicAdd(&out[ir * NXY + jr], acc2 * SC);   // P2 = (511-iq, 511-jq)
    unsafeAtomicAdd(&out[jr * NXY + iq], acc3 * SC);   // P3 = (511-jq, iq)
}

extern "C" void kernel_launch(void* const* d_in, const int* in_sizes, int n_in,
                              void* d_out, int out_size, void* d_ws, size_t ws_size,
                              hipStream_t stream) {
    const float* sino = (const float*)d_in[0];
    float* out = (float*)d_out;
    float* Q = (float*)d_ws;                                           // 720*768*4 = 2.21 MB
    float4* trig = (float4*)((char*)d_ws + (size_t)NV * NUP * sizeof(float)); // 16B-aligned

    filter_kernel<<<NV / 4, 192, 0, stream>>>(sino, Q, trig, out);     // also zeroes out
    bp_kernel<<<4096, 256, 0, stream>>>(Q, trig, out);
}

// Round 17
// 116.155 us; speedup vs baseline: 1.1432x; 1.1432x over previous
//
#include <hip/hip_runtime.h>
#include <math.h>

#define NV 720
#define NU 736
#define NUP 768      // padded Q row stride (bins 736..767 never gathered)
#define NXY 512

// ---------------- Stage 1+2: cosine weight + Ram-Lak Toeplitz GEMM (+ trig, + out=0) ---
// R17: j-split x2 — 360 blocks; block (vb, half) computes outputs r in {2*half, 2*half+1}
// for view-group vb (4 views). Each output's 368-tap summation order is UNCHANGED
// (no reassociation) -> Q bit-identical to R15. Doubles parallelism, halves per-iter work.
__global__ __launch_bounds__(192) void filter_kernel(const float* __restrict__ sino,
                                                     float* __restrict__ Q,
                                                     float4* __restrict__ trig,
                                                     float* __restrict__ out_zero) {
    __shared__ float s4[2][368][4];   // [parity][m][view]
    __shared__ float wco[736];        // wco[i] = -1/(pi*(2i-735)*DU)^2
    const int half = blockIdx.x & 1;  // output-half: r in {2h, 2h+1}
    const int vb = blockIdx.x >> 1;
    const int v0 = vb * 4;
    const int t = threadIdx.x;

    // zero the atomic target (replaces the hipMemsetAsync dispatch; bp launches after)
    for (int i = blockIdx.x * 192 + t; i < NXY * NXY; i += 360 * 192)
        out_zero[i] = 0.0f;

    if (half == 0 && t < 4) {
        int v = v0 + t;
        float beta = (float)((double)v * (2.0 * M_PI / 720.0));
        float cb = cosf(beta), sb = sinf(beta);
        const float K = (float)(1085.6 / 1.2858);   // DSD/DU
        trig[v] = make_float4(cb * K, sb * K, cb, sb);
    }
    for (int i = t; i < 736; i += 192) {
        double n = (double)(2 * i - 735);
        double a = M_PI * n * 1.2858;
        wco[i] = (float)(-1.0 / (a * a));
    }
    const float DSD2 = (float)(1085.6 * 1085.6);
    for (int vv = 0; vv < 4; ++vv) {
        for (int u = t; u < 736; u += 192) {
            float us = ((float)u - 367.5f) * 1.2858f;
            float cw = 1085.6f / sqrtf(DSD2 + us * us);
            s4[u & 1][u >> 1][vv] = sino[(v0 + vv) * NU + u] * cw;
        }
    }
    __syncthreads();

    if (t < 184) {
        const int pj = (t < 92) ? 1 : 0;
        const int J0 = (t < 92) ? t : t - 92;
        const int q = 1 - pj;
        const int rb = half * 2;              // this block's r-range: rb, rb+1
        float acc[2][4];
        #pragma unroll
        for (int r = 0; r < 2; ++r)
            #pragma unroll
            for (int vv = 0; vv < 4; ++vv) acc[r][vv] = 0.0f;

        const int ibase0 = J0 + 367 + pj;
        #pragma unroll 4
        for (int m = 0; m < 368; ++m) {
            const float4 sv = *(const float4*)&s4[q][m][0];
            const int ib = ibase0 - m;
            const float w0 = wco[ib + 92 * rb];
            const float w1 = wco[ib + 92 * rb + 92];
            acc[0][0] = fmaf(w0, sv.x, acc[0][0]);
            acc[0][1] = fmaf(w0, sv.y, acc[0][1]);
            acc[0][2] = fmaf(w0, sv.z, acc[0][2]);
            acc[0][3] = fmaf(w0, sv.w, acc[0][3]);
            acc[1][0] = fmaf(w1, sv.x, acc[1][0]);
            acc[1][1] = fmaf(w1, sv.y, acc[1][1]);
            acc[1][2] = fmaf(w1, sv.z, acc[1][2]);
            acc[1][3] = fmaf(w1, sv.w, acc[1][3]);
        }
        const float H0 = (float)(1.0 / (4.0 * 1.2858 * 1.2858));
        #pragma unroll
        for (int r = 0; r < 2; ++r) {
            const float4 c = *(const float4*)&s4[pj][J0 + 92 * (rb + r)][0];
            acc[r][0] = fmaf(H0, c.x, acc[r][0]);
            acc[r][1] = fmaf(H0, c.y, acc[r][1]);
            acc[r][2] = fmaf(H0, c.z, acc[r][2]);
            acc[r][3] = fmaf(H0, c.w, acc[r][3]);
        }
        #pragma unroll
        for (int r = 0; r < 2; ++r) {
            const int j = 2 * (J0 + 92 * (rb + r)) + pj;
            #pragma unroll
            for (int vv = 0; vv < 4; ++vv)
                Q[(v0 + vv) * NUP + j] = acc[r][vv] * 1.2858f;
        }
    }
}

// ---------------- Stage 3: backprojection — R15 VERBATIM (54.5us, passed) --------------
// R16 lesson: address-dependent VMEM in the hot loop exposes ~200cyc L2 latency per
// iter (70us regression) — only pre-staged LDS fetches belong in the gather loop.
// R14: DS-crossbar is the binding resource; ds_read2 per bilinear gather. R15: dbuf.
// Lessons: no gate-chain reassociation (R4); 1 px/lane (R5); no branch-wrapped or
// address-dependent in-loop VMEM (R12/R16).
__global__ __launch_bounds__(256) void bp_kernel(const float* __restrict__ Q,
                                                 const float4* __restrict__ trig,
                                                 float* __restrict__ out) {
    __shared__ float win[2][4][NUP];          // 24 KB double buffer
    const int b = blockIdx.x;
    const int c = b & 15;                     // view chunk: base views {c, c+16, ...}
    const int blk = b >> 4;                   // 256 quadrant blocks of 16x16
    const int bx = blk >> 4;
    const int by = blk & 15;
    const int t = threadIdx.x;
    const int w = t >> 6;
    const int l = t & 63;
    const int iq = (bx << 4) + ((w >> 1) << 3) + (l >> 3);   // [0,256)
    const int jq = (by << 4) + ((w & 1) << 3) + (l & 7);     // [0,256)

    const float dx = 400.0f / 512.0f;         // 0.78125 exact
    const float X = ((float)iq - 255.5f) * dx;   // < 0
    const float Y = ((float)jq - 255.5f) * dx;   // < 0
    const float Kc = (float)(1085.6 / 1.2858);

    float acc0 = 0.0f, acc1 = 0.0f, acc2 = 0.0f, acc3 = 0.0f;
    const bool inr = fmaf(X, X, Y * Y) <= 236.5f * 236.5f;
    const bool myint = __all(inr);

    const int nk = (c < 4) ? 12 : 11;         // ceil((180-c)/16)
    const float* rowp = Q + (size_t)(c + 180 * w) * NUP;   // wave w stages row w
    const float4* tvp = trig + c;

    // preload iter 0 into buffer 0
    #pragma unroll
    for (int ch = 0; ch < 3; ++ch)
        __builtin_amdgcn_global_load_lds(
            (const __attribute__((address_space(1))) void*)(rowp + ch * 256 + l * 4),
            (__attribute__((address_space(3))) void*)&win[0][w][ch * 256],
            16, 0, 0);

    for (int it = 0; it < nk; ++it) {
        __syncthreads();                      // win[it&1] staged; prior reads of it^1 done
        if (it + 1 < nk) {
            const float* rn = rowp + 16 * NUP;
            #pragma unroll
            for (int ch = 0; ch < 3; ++ch)
                __builtin_amdgcn_global_load_lds(
                    (const __attribute__((address_space(1))) void*)(rn + ch * 256 + l * 4),
                    (__attribute__((address_space(3))) void*)&win[(it + 1) & 1][w][ch * 256],
                    16, 0, 0);
        }
        const float* winf = &win[it & 1][0][0];

        if (myint) {
            // ---- interior: symmetric geometry (R10-proven), ds_read2 gathers ---------
            const float4 tv = tvp[0];                     // cb = tv.z, sb = tv.w
            float a = fmaf(tv.z, X, tv.w * Y);            // t0
            float bb = fmaf(tv.z, Y, -tv.w * X);          // s0
            float aK = a * Kc, bK = bb * Kc;
            float D0 = 595.0f - bb, D1 = 595.0f + a, D2 = 595.0f + bb, D3 = 595.0f - a;
            float r0 = __builtin_amdgcn_rcpf(D0);
            float r1 = __builtin_amdgcn_rcpf(D1);
            float r2 = __builtin_amdgcn_rcpf(D2);
            float r3 = __builtin_amdgcn_rcpf(D3);
            float fi0 = fmaf(aK,  r0, 367.5f);
            float fi1 = fmaf(bK,  r1, 367.5f);
            float fi2 = fmaf(-aK, r2, 367.5f);
            float fi3 = fmaf(-bK, r3, 367.5f);
            int im[4] = {(int)fi0, (int)fi1, (int)fi2, (int)fi3};  // in [1,733]
            float ff[4] = {__builtin_amdgcn_fractf(fi0), __builtin_amdgcn_fractf(fi1),
                           __builtin_amdgcn_fractf(fi2), __builtin_amdgcn_fractf(fi3)};
            float gg[4] = {r0 * r0, r1 * r1, r2 * r2, r3 * r3};
            float* accp[4] = {&acc0, &acc1, &acc2, &acc3};
            #pragma unroll
            for (int m = 0; m < 4; ++m) {
                #pragma unroll
                for (int k = 0; k < 4; ++k) {
                    const float* p = winf + (k * NUP + im[m]);
                    float q0 = p[0];                      // ds_read2_b32 (fused pair)
                    float q1 = p[1];
                    float val = fmaf(ff[m], q1 - q0, q0);
                    *accp[(m - k) & 3] = fmaf(gg[m], val, *accp[(m - k) & 3]);
                }
            }
        } else {
            // ---- exterior: R3-exact chains/gates per pixel, staged ds_read2 fetch ----
            const float4 tvs[4] = {tvp[0], tvp[180], tvp[360], tvp[540]};
            const float pX[4] = {X, Y, -X, -Y};
            const float pY[4] = {Y, -X, -Y, X};
            float* accp[4] = {&acc0, &acc1, &acc2, &acc3};
            #pragma unroll
            for (int j = 0; j < 4; ++j) {
                float Xm = pX[j], Ym = pY[j];
                #pragma unroll
                for (int k = 0; k < 4; ++k) {
                    const float4 tv = tvs[k];
                    float t2 = fmaf(tv.x, Xm, tv.y * Ym);               // R3-exact
                    float D  = fmaf(tv.w, Xm, fmaf(tv.z, -Ym, 595.0f)); // R3-exact
                    float rD = __builtin_amdgcn_rcpf(D);
                    float fidx = fmaf(t2, rD, 367.5f);
                    int i0c = min(max((int)fidx, 0), NU - 2);           // v_med3_i32
                    float f = __builtin_amdgcn_fractf(fidx);
                    const float* p = winf + (k * NUP + i0c);
                    float q0 = p[0];                                    // ds_read2_b32
                    float q1 = p[1];
                    float val = fmaf(f, q1 - q0, q0);
                    float cen = fidx - 367.5f;                          // R3-exact gate
                    float g = (__builtin_fabsf(cen) <= 367.5f) ? rD * rD : 0.0f;
                    *accp[j] = fmaf(g, val, *accp[j]);
                }
            }
        }
        rowp += 16 * NUP;
        tvp += 16;
    }
    const float SC = (float)(595.0 * 595.0 * 0.5 * (2.0 * M_PI / 720.0));
    const int ir = 511 - iq, jr = 511 - jq;
    unsafeAtomicAdd(&out[iq * NXY + jq], acc0 * SC);   // P0 = (iq, jq)
    unsafeAtomicAdd(&out[jq * NXY + ir], acc1 * SC);   // P1 = (jq, 511-iq)
    unsafeAtomicAdd(&out[ir * NXY + jr], acc2 * SC);   // P2 = (511-iq, 511-jq)
    unsafeAtomicAdd(&out[jr * NXY + iq], acc3 * SC);   // P3 = (511-jq, iq)
}

extern "C" void kernel_launch(void* const* d_in, const int* in_sizes, int n_in,
                              void* d_out, int out_size, void* d_ws, size_t ws_size,
                              hipStream_t stream) {
    const float* sino = (const float*)d_in[0];
    float* out = (float*)d_out;
    float* Q = (float*)d_ws;                                           // 720*768*4 = 2.21 MB
    float4* trig = (float4*)((char*)d_ws + (size_t)NV * NUP * sizeof(float)); // 16B-aligned

    filter_kernel<<<360, 192, 0, stream>>>(sino, Q, trig, out);        // also zeroes out
    bp_kernel<<<4096, 256, 0, stream>>>(Q, trig, out);
}